// Round 7
// baseline (478.113 us; speedup 1.0000x reference)
//
#include <hip/hip_runtime.h>
#include <cstdint>
#include <cstddef>

typedef __bf16 bf16;
typedef __bf16 bf16x8 __attribute__((ext_vector_type(8)));
typedef float  f32x4  __attribute__((ext_vector_type(4)));

static_assert(sizeof(bf16x8) == 16, "bf16x8 must be 16B");

// async global->LDS, 16B per lane; lane i's data lands at ldsbase + i*16.
__device__ __forceinline__ void async_copy16(const bf16* g, bf16* l) {
  __builtin_amdgcn_global_load_lds(
      (__attribute__((address_space(1))) void*)(g),
      (__attribute__((address_space(3))) void*)(l),
      16, 0, 0);
}

__device__ __forceinline__ uint32_t lds_u32(const bf16* p) {
  return (uint32_t)(uintptr_t)((__attribute__((address_space(3))) const bf16*)p);
}

// fp32 -> bf16 bulk convert, 8 elems/thread. n must be a multiple of 2048.
__global__ __launch_bounds__(256)
void conv_f32_bf16(const float* __restrict__ s, bf16* __restrict__ d) {
  const size_t i = ((size_t)blockIdx.x * 256 + threadIdx.x) * 8;
  const f32x4 a = *(const f32x4*)(s + i);
  const f32x4 b = *(const f32x4*)(s + i + 4);
  bf16x8 o;
#pragma unroll
  for (int e = 0; e < 4; ++e) { o[e] = (bf16)a[e]; o[4 + e] = (bf16)b[e]; }
  *(bf16x8*)(d + i) = o;
}

// ---------------------------------------------------------------------------
// QKV GEMM (FROZEN CONTROL, R6): 128(M) x 256(N), BK=32, 5-deep rotating.
// 512 threads (8 waves 2Mx4N, wave tile 64x64). C[m,n] = sum_k A[m,k]*W[n,k].
// ---------------------------------------------------------------------------
template<int AMODE>
__device__ __forceinline__ void stageA32(const bf16* __restrict__ P, int K,
                                         int row0, int k0,
                                         bf16* lds, int wave, int lane) {
  const int lin0 = wave * 64;           // wave-uniform
  const int lin  = lin0 + lane;
  const int row  = lin >> 2;            // 0..127
  const int ch   = lin & 3;
  const int gch  = ch ^ ((row >> 1) & 3);
  const bf16* src;
  if constexpr (AMODE == 2) {
    const int rowA = row0 + row;
    const int b = rowA >> 11, s = rowA & 2047;
    src = P + ((size_t)(b * 16 + (k0 >> 7)) * 2048 + s) * 128 + (k0 & 127) + gch * 8;
  } else {
    src = P + (size_t)(row0 + row) * K + k0 + gch * 8;
  }
  async_copy16(src, lds + lin0 * 8);
}

__device__ __forceinline__ void stageW32(const bf16* __restrict__ P, int K,
                                         int row0, int k0,
                                         bf16* lds, int wave, int lane) {
#pragma unroll
  for (int i = 0; i < 2; ++i) {
    const int lin0 = i * 512 + wave * 64;
    const int lin  = lin0 + lane;
    const int row  = lin >> 2;          // 0..255
    const int ch   = lin & 3;
    const int gch  = ch ^ ((row >> 1) & 3);
    async_copy16(P + (size_t)(row0 + row) * K + k0 + gch * 8,
                 lds + lin0 * 8);
  }
}

__device__ __forceinline__ void ld_frags(uint32_t ab, uint32_t bb,
                                         bf16x8 (&a)[4], bf16x8 (&b)[4]) {
  asm volatile("ds_read_b128 %0, %1 offset:0"    : "=v"(a[0]) : "v"(ab));
  asm volatile("ds_read_b128 %0, %1 offset:1024" : "=v"(a[1]) : "v"(ab));
  asm volatile("ds_read_b128 %0, %1 offset:2048" : "=v"(a[2]) : "v"(ab));
  asm volatile("ds_read_b128 %0, %1 offset:3072" : "=v"(a[3]) : "v"(ab));
  asm volatile("ds_read_b128 %0, %1 offset:0"    : "=v"(b[0]) : "v"(bb));
  asm volatile("ds_read_b128 %0, %1 offset:1024" : "=v"(b[1]) : "v"(bb));
  asm volatile("ds_read_b128 %0, %1 offset:2048" : "=v"(b[2]) : "v"(bb));
  asm volatile("ds_read_b128 %0, %1 offset:3072" : "=v"(b[3]) : "v"(bb));
}

template<int AMODE, int CMODE>
__global__ __launch_bounds__(512, 2)
void gemm_bt3(const bf16* __restrict__ A, const bf16* __restrict__ W,
              float* __restrict__ Crow, bf16* __restrict__ Cq,
              bf16* __restrict__ Ck, bf16* __restrict__ Cvt,
              int M, int N, int K, int nbase) {
  __shared__ bf16 As[5][128 * 32];
  __shared__ bf16 Ws[5][256 * 32];

  const int tid  = threadIdx.x;
  const int wave = tid >> 6, lane = tid & 63;
  const int quad = lane >> 4, r = lane & 15;
  const int wr = wave >> 2, wc = wave & 3;   // 2M x 4N wave grid

  const int gx  = gridDim.x;
  const int nwg = gx * gridDim.y;
  int wg = blockIdx.y * gx + blockIdx.x;
  wg = (wg & 7) * (nwg >> 3) + (wg >> 3);
  const int m0 = (wg / gx) * 128;
  const int n0 = (wg % gx) * 256;

  const int wm = wr * 64, wn = wc * 64;
  const int nT = K >> 5;
  const int cs = quad ^ ((r >> 1) & 3);      // read chunk (A and W)

  f32x4 acc[4][4] = {};

  const uint32_t a_rd = lds_u32(&As[0][0]) + (((wm + r) * 32 + cs * 8) << 1);
  const uint32_t b_rd = lds_u32(&Ws[0][0]) + (((wn + r) * 32 + cs * 8) << 1);

  // prologue: stage tiles 0..3 (12 load-instrs)
#pragma unroll
  for (int i = 0; i < 4; ++i)
    if (i < nT) {
      stageA32<AMODE>(A, K, m0, i << 5, &As[i][0], wave, lane);
      stageW32(W, K, n0, i << 5, &Ws[i][0], wave, lane);
    }
  if (nT > 3)       asm volatile("s_waitcnt vmcnt(9)" ::: "memory");
  else if (nT == 3) asm volatile("s_waitcnt vmcnt(6)" ::: "memory");
  else if (nT == 2) asm volatile("s_waitcnt vmcnt(3)" ::: "memory");
  else              asm volatile("s_waitcnt vmcnt(0)" ::: "memory");
  __builtin_amdgcn_sched_barrier(0);
  __builtin_amdgcn_s_barrier();

  int bc = 0;   // t % 5 (read buf)
  int bs = 4;   // (t+4) % 5 (stage buf)
  for (int t = 0; t < nT; ++t) {
    bf16x8 af[4], bw[4];
    ld_frags(a_rd + bc * 8192, b_rd + bc * 16384, af, bw);
    if (t + 4 < nT) {
      stageA32<AMODE>(A, K, m0, (t + 4) << 5, &As[bs][0], wave, lane);
      stageW32(W, K, n0, (t + 4) << 5, &Ws[bs][0], wave, lane);
      asm volatile("s_waitcnt vmcnt(9)" ::: "memory");   // tile t+1 landed
    } else if (t + 4 == nT) {
      asm volatile("s_waitcnt vmcnt(6)" ::: "memory");
    } else if (t + 3 == nT) {
      asm volatile("s_waitcnt vmcnt(3)" ::: "memory");
    } else {
      asm volatile("s_waitcnt vmcnt(0)" ::: "memory");
    }
    __builtin_amdgcn_sched_barrier(0);
    asm volatile("s_waitcnt lgkmcnt(0)" ::: "memory");
    __builtin_amdgcn_sched_barrier(0);
    __builtin_amdgcn_s_setprio(1);
#pragma unroll
    for (int m = 0; m < 4; ++m)
#pragma unroll
      for (int n = 0; n < 4; ++n)
        acc[m][n] = __builtin_amdgcn_mfma_f32_16x16x32_bf16(af[m], bw[n], acc[m][n], 0, 0, 0);
    __builtin_amdgcn_s_setprio(0);
    __builtin_amdgcn_s_barrier();
    bc = (bc + 1 == 5) ? 0 : bc + 1;
    bs = (bs + 1 == 5) ? 0 : bs + 1;
  }

#pragma unroll
  for (int i = 0; i < 4; ++i) {
    const int growb = m0 + wm + i * 16 + quad * 4;
#pragma unroll
    for (int j = 0; j < 4; ++j) {
      const int gcol = n0 + wn + j * 16 + r;
#pragma unroll
      for (int rg = 0; rg < 4; ++rg) {
        const int grow = growb + rg;
        if constexpr (CMODE == 1) {
          const int gc = nbase + gcol;
          const int which = gc >> 11;
          const int h = (gc >> 7) & 15;
          const int d = gc & 127;
          const int b = grow >> 11;
          const int s = grow & 2047;
          const bf16 v = (bf16)acc[i][j][rg];
          if (which == 0)
            Cq[(((size_t)b * 16 + h) * 2048 + s) * 128 + d] = v;
          else if (which == 1)
            Ck[(((size_t)b * 16 + h) * 2048 + s) * 128 + d] = v;
          else
            Cvt[(((size_t)b * 16 + h) * 128 + d) * 2048 + s] = v;  // transposed
        } else {
          Crow[(size_t)grow * N + gcol] = acc[i][j][rg];
        }
      }
    }
  }
}

// ---------------------------------------------------------------------------
// A/B EXPERIMENT (proj only): 256x256, BK=32, 4-deep rotating prefetch.
// LDS As[4][256*32] + Ws[4][256*32] = 128KB, 1 block/CU. acc[8][4] (~216 VGPR
// est). Staged bytes per GEMM: 256MB vs 384MB for 128x256 (intensity +50%).
// Grid (8,16)=128 blocks (half-idle CUs — the test: if staging-path-bound,
// wall time drops to ~40us; if compute-bound at half grid, ~55us; if R3's
// 256^2 failure was structural, ~80us).
// vmcnt ledger: 4 instrs/tile; phase t stages t+3 into buf (t+3)%4 (freed at
// end of phase t-1); vmcnt(8) allows tiles t+2,t+3 in flight, forces t+1
// (issued ~3 phases = ~3000cy ago) landed. Tails 4 -> 0 -> 0.
// ---------------------------------------------------------------------------
template<int AMODE>
__device__ __forceinline__ void stage256(const bf16* __restrict__ P, int K,
                                         int row0, int k0,
                                         bf16* lds, int wave, int lane) {
#pragma unroll
  for (int i = 0; i < 2; ++i) {
    const int lin0 = i * 512 + wave * 64;
    const int lin  = lin0 + lane;
    const int row  = lin >> 2;          // 0..255
    const int ch   = lin & 3;
    const int gch  = ch ^ ((row >> 1) & 3);
    const bf16* src;
    if constexpr (AMODE == 2) {
      const int rowA = row0 + row;
      const int b = rowA >> 11, s = rowA & 2047;
      src = P + ((size_t)(b * 16 + (k0 >> 7)) * 2048 + s) * 128 + (k0 & 127) + gch * 8;
    } else {
      src = P + (size_t)(row0 + row) * K + k0 + gch * 8;
    }
    async_copy16(src, lds + lin0 * 8);
  }
}

__device__ __forceinline__ void ld_frags84(uint32_t ab, uint32_t bb,
                                           bf16x8 (&a)[8], bf16x8 (&b)[4]) {
  asm volatile("ds_read_b128 %0, %1 offset:0"    : "=v"(a[0]) : "v"(ab));
  asm volatile("ds_read_b128 %0, %1 offset:1024" : "=v"(a[1]) : "v"(ab));
  asm volatile("ds_read_b128 %0, %1 offset:2048" : "=v"(a[2]) : "v"(ab));
  asm volatile("ds_read_b128 %0, %1 offset:3072" : "=v"(a[3]) : "v"(ab));
  asm volatile("ds_read_b128 %0, %1 offset:4096" : "=v"(a[4]) : "v"(ab));
  asm volatile("ds_read_b128 %0, %1 offset:5120" : "=v"(a[5]) : "v"(ab));
  asm volatile("ds_read_b128 %0, %1 offset:6144" : "=v"(a[6]) : "v"(ab));
  asm volatile("ds_read_b128 %0, %1 offset:7168" : "=v"(a[7]) : "v"(ab));
  asm volatile("ds_read_b128 %0, %1 offset:0"    : "=v"(b[0]) : "v"(bb));
  asm volatile("ds_read_b128 %0, %1 offset:1024" : "=v"(b[1]) : "v"(bb));
  asm volatile("ds_read_b128 %0, %1 offset:2048" : "=v"(b[2]) : "v"(bb));
  asm volatile("ds_read_b128 %0, %1 offset:3072" : "=v"(b[3]) : "v"(bb));
}

template<int AMODE, int CMODE>
__global__ __launch_bounds__(512, 2)
void gemm256r(const bf16* __restrict__ A, const bf16* __restrict__ W,
              float* __restrict__ Crow, bf16* __restrict__ Cq,
              bf16* __restrict__ Ck, bf16* __restrict__ Cvt,
              int M, int N, int K, int nbase) {
  __shared__ bf16 As[4][256 * 32];
  __shared__ bf16 Ws[4][256 * 32];

  const int tid  = threadIdx.x;
  const int wave = tid >> 6, lane = tid & 63;
  const int quad = lane >> 4, r = lane & 15;
  const int wr = wave >> 2, wc = wave & 3;   // 2M x 4N, wave tile 128x64

  const int gx  = gridDim.x;
  const int nwg = gx * gridDim.y;
  int wg = blockIdx.y * gx + blockIdx.x;
  wg = (wg & 7) * (nwg >> 3) + (wg >> 3);
  const int m0 = (wg / gx) * 256;
  const int n0 = (wg % gx) * 256;

  const int wm = wr * 128, wn = wc * 64;
  const int nT = K >> 5;
  const int cs = quad ^ ((r >> 1) & 3);

  f32x4 acc[8][4] = {};

  const uint32_t a_rd = lds_u32(&As[0][0]) + (((wm + r) * 32 + cs * 8) << 1);
  const uint32_t b_rd = lds_u32(&Ws[0][0]) + (((wn + r) * 32 + cs * 8) << 1);

  // prologue: stage tiles 0..2 (12 load-instrs)
#pragma unroll
  for (int i = 0; i < 3; ++i)
    if (i < nT) {
      stage256<AMODE>(A, K, m0, i << 5, &As[i][0], wave, lane);
      stage256<0>(W, K, n0, i << 5, &Ws[i][0], wave, lane);
    }
  if (nT > 2)       asm volatile("s_waitcnt vmcnt(8)" ::: "memory");
  else if (nT == 2) asm volatile("s_waitcnt vmcnt(4)" ::: "memory");
  else              asm volatile("s_waitcnt vmcnt(0)" ::: "memory");
  __builtin_amdgcn_sched_barrier(0);
  __builtin_amdgcn_s_barrier();

  int bc = 0;   // t % 4
  int bs = 3;   // (t+3) % 4
  for (int t = 0; t < nT; ++t) {
    bf16x8 af[8], bw[4];
    ld_frags84(a_rd + bc * 16384, b_rd + bc * 16384, af, bw);
    if (t + 3 < nT) {
      stage256<AMODE>(A, K, m0, (t + 3) << 5, &As[bs][0], wave, lane);
      stage256<0>(W, K, n0, (t + 3) << 5, &Ws[bs][0], wave, lane);
      asm volatile("s_waitcnt vmcnt(8)" ::: "memory");   // tile t+1 landed
    } else if (t + 3 == nT) {
      asm volatile("s_waitcnt vmcnt(4)" ::: "memory");
    } else {
      asm volatile("s_waitcnt vmcnt(0)" ::: "memory");
    }
    __builtin_amdgcn_sched_barrier(0);
    asm volatile("s_waitcnt lgkmcnt(0)" ::: "memory");
    __builtin_amdgcn_sched_barrier(0);
    __builtin_amdgcn_s_setprio(1);
#pragma unroll
    for (int m = 0; m < 8; ++m)
#pragma unroll
      for (int n = 0; n < 4; ++n)
        acc[m][n] = __builtin_amdgcn_mfma_f32_16x16x32_bf16(af[m], bw[n], acc[m][n], 0, 0, 0);
    __builtin_amdgcn_s_setprio(0);
    __builtin_amdgcn_s_barrier();
    bc = (bc + 1) & 3;
    bs = (bs + 1) & 3;
  }

#pragma unroll
  for (int i = 0; i < 8; ++i) {
    const int growb = m0 + wm + i * 16 + quad * 4;
#pragma unroll
    for (int j = 0; j < 4; ++j) {
      const int gcol = n0 + wn + j * 16 + r;
#pragma unroll
      for (int rg = 0; rg < 4; ++rg) {
        const int grow = growb + rg;
        if constexpr (CMODE == 1) {
          const int gc = nbase + gcol;
          const int which = gc >> 11;
          const int h = (gc >> 7) & 15;
          const int d = gc & 127;
          const int b = grow >> 11;
          const int s = grow & 2047;
          const bf16 v = (bf16)acc[i][j][rg];
          if (which == 0)
            Cq[(((size_t)b * 16 + h) * 2048 + s) * 128 + d] = v;
          else if (which == 1)
            Ck[(((size_t)b * 16 + h) * 2048 + s) * 128 + d] = v;
          else
            Cvt[(((size_t)b * 16 + h) * 128 + d) * 2048 + s] = v;
        } else {
          Crow[(size_t)grow * N + gcol] = acc[i][j][rg];
        }
      }
    }
  }
}

// Flash attention, causal. Split into TWO balanced dispatches (observability:
// each half ~57us < GEMM ~66us so GEMM counters surface in top-5).
// ibase=0: pairs {31-x, x} x=0..7; ibase=8: pairs {23-x, 8+x} x=0..7.
// Every block = exactly 33 KV-tiles. 256 blocks/dispatch = 1 block/CU.
__global__ __launch_bounds__(256, 2)
void attn_kernel(bf16* __restrict__ Q, const bf16* __restrict__ K,
                 const bf16* __restrict__ Vt, int S, int ibase) {
  __shared__ bf16 k_lds[2][64 * 128];   // [kv][d], swizzled   32 KB
  __shared__ bf16 v_lds[2][128 * 64];   // [d][kv], swizzled   32 KB
  __shared__ bf16 p_lds[4][16 * 64];    // per-wave P           8 KB

  const int tid = threadIdx.x, wave = tid >> 6, lane = tid & 63;
  const int quad = lane >> 4, r = lane & 15;
  const int bh = blockIdx.y;
  bf16* Qh = Q + (size_t)bh * S * 128;
  const bf16* Kh = K + (size_t)bh * S * 128;
  const bf16* Vth = Vt + (size_t)bh * 128 * S;

  const float sc = 0.0883883476483184f * 1.4426950408889634f; // 1/sqrt(128)*log2e

  auto issue_stage = [&](int kv0, int buf) {
#pragma unroll
    for (int j = 0; j < 4; ++j) {
      const int lin0 = j * 256 + wave * 64;       // wave-uniform
      const int lin = lin0 + lane;
      const int row = lin >> 4, ch = lin & 15;    // K: [64 kv][16 chunks]
      async_copy16(Kh + (size_t)(kv0 + row) * 128 + ((ch ^ (row & 7)) << 3),
                   &k_lds[buf][0] + lin0 * 8);
    }
#pragma unroll
    for (int j = 0; j < 4; ++j) {
      const int lin0 = j * 256 + wave * 64;
      const int lin = lin0 + lane;
      const int row = lin >> 3, c = lin & 7;      // V^T: [128 d][8 chunks]
      async_copy16(Vth + (size_t)row * S + kv0 + ((c ^ (row & 7)) << 3),
                   &v_lds[buf][0] + lin0 * 8);
    }
  };

  const int i0 = ibase + blockIdx.x;
  for (int pass = 0; pass < 2; ++pass) {
    const int qb = pass ? i0 : (31 - i0);  // heavy tile first
    const int q0 = qb << 6;
    const int qrow0 = q0 + wave * 16;   // 16 q-rows per wave, 4 waves = 64
    const int nkv = qb + 1;

    bf16x8 qf[4];
    for (int ks = 0; ks < 4; ++ks)
      qf[ks] = *(const bf16x8*)(Qh + (size_t)(qrow0 + r) * 128 + ks * 32 + quad * 8);

    f32x4 o_acc[8] = {};
    f32x4 m_run, l_run;
    for (int t = 0; t < 4; ++t) { m_run[t] = -1e30f; l_run[t] = 0.f; }

    issue_stage(0, 0);  // prologue (prev pass fully drained by its tail)

    for (int kt = 0; kt < nkv; ++kt) {
      const int kv0 = kt << 6;
      const int cur = kt & 1;
      if (kt + 1 < nkv) {
        issue_stage((kt + 1) << 6, cur ^ 1);
        asm volatile("s_waitcnt vmcnt(8)" ::: "memory");  // cur tile resident
      } else {
        asm volatile("s_waitcnt vmcnt(0)" ::: "memory");
      }
      __builtin_amdgcn_sched_barrier(0);
      __syncthreads();

      {
        // S = Q K^T
        f32x4 sa[4] = {};
        __builtin_amdgcn_s_setprio(1);
        for (int ks = 0; ks < 4; ++ks) {
          bf16x8 kf[4];
          for (int nt = 0; nt < 4; ++nt) {
            const int kr = nt * 16 + r;
            kf[nt] = *(const bf16x8*)(&k_lds[cur][0] + kr * 128 + (((ks * 4 + quad) ^ (kr & 7)) << 3));
          }
          for (int nt = 0; nt < 4; ++nt)
            sa[nt] = __builtin_amdgcn_mfma_f32_16x16x32_bf16(qf[ks], kf[nt], sa[nt], 0, 0, 0);
        }
        __builtin_amdgcn_s_setprio(0);
        // causal mask on diagonal tiles
        if (kv0 + 63 > qrow0) {
          for (int nt = 0; nt < 4; ++nt) {
            const int col  = kv0 + nt * 16 + r;
            const int rowb = qrow0 + quad * 4;
            for (int rg = 0; rg < 4; ++rg)
              if (col > rowb + rg) sa[nt][rg] = -1e30f;
          }
        }
        // online softmax (each score row lives on the 16 lanes of one quad)
        f32x4 mx = sa[0];
        for (int nt = 1; nt < 4; ++nt)
          for (int rg = 0; rg < 4; ++rg) mx[rg] = fmaxf(mx[rg], sa[nt][rg]);
        for (int off = 1; off < 16; off <<= 1)
          for (int rg = 0; rg < 4; ++rg) mx[rg] = fmaxf(mx[rg], __shfl_xor(mx[rg], off, 64));
        // T13 defer-max: rescale only when growth is material (P <= 2^8).
        float need = mx[0] - m_run[0];
        for (int rg = 1; rg < 4; ++rg) need = fmaxf(need, mx[rg] - m_run[rg]);
        if (need * sc > 8.0f) {
          f32x4 alpha;
          for (int rg = 0; rg < 4; ++rg) {
            const float mnew = fmaxf(m_run[rg], mx[rg]);
            alpha[rg] = exp2f((m_run[rg] - mnew) * sc);
            m_run[rg] = mnew;
            l_run[rg] *= alpha[rg];
          }
          for (int nt2 = 0; nt2 < 8; ++nt2)
            for (int rg = 0; rg < 4; ++rg) o_acc[nt2][rg] *= alpha[rg];
        }
        f32x4 rsum = {0.f, 0.f, 0.f, 0.f};
        for (int nt = 0; nt < 4; ++nt)
          for (int rg = 0; rg < 4; ++rg) {
            const float p = exp2f((sa[nt][rg] - m_run[rg]) * sc);
            sa[nt][rg] = p;
            rsum[rg] += p;
          }
        for (int off = 1; off < 16; off <<= 1)
          for (int rg = 0; rg < 4; ++rg) rsum[rg] += __shfl_xor(rsum[rg], off, 64);
        for (int rg = 0; rg < 4; ++rg) l_run[rg] += rsum[rg];
        // P: C-layout -> A-layout via per-wave LDS round-trip, swizzled
        for (int nt = 0; nt < 4; ++nt)
          for (int rg = 0; rg < 4; ++rg) {
            const int prow = quad * 4 + rg;
            const int pcol = nt * 16 + r;
            p_lds[wave][prow * 64 + (((pcol >> 3) ^ (prow & 7)) * 8) + (pcol & 7)] =
                (bf16)sa[nt][rg];
          }
        // O += P V
        __builtin_amdgcn_s_setprio(1);
        for (int ks2 = 0; ks2 < 2; ++ks2) {
          const int prow = r;
          const bf16x8 pf = *(const bf16x8*)(p_lds[wave] + prow * 64 + (((ks2 * 4 + quad) ^ (prow & 7)) * 8));
          for (int nt2 = 0; nt2 < 8; ++nt2) {
            const int vrow = nt2 * 16 + r;
            const bf16x8 vf = *(const bf16x8*)(&v_lds[cur][0] + vrow * 64 + (((ks2 * 4 + quad) ^ (vrow & 7)) * 8));
            o_acc[nt2] = __builtin_amdgcn_mfma_f32_16x16x32_bf16(pf, vf, o_acc[nt2], 0, 0, 0);
          }
        }
        __builtin_amdgcn_s_setprio(0);
      }
      __syncthreads();
    }

    // epilogue: write O back into the Q plane, same [b,h,s,d] coords
    f32x4 inv;
    for (int rg = 0; rg < 4; ++rg) inv[rg] = 1.0f / l_run[rg];
    for (int nt2 = 0; nt2 < 8; ++nt2) {
      const int d = nt2 * 16 + r;
      for (int rg = 0; rg < 4; ++rg) {
        const int s = qrow0 + quad * 4 + rg;
        Qh[(size_t)s * 128 + d] = (bf16)(o_acc[nt2][rg] * inv[rg]);
      }
    }
  }
}

extern "C" void kernel_launch(void* const* d_in, const int* in_sizes, int n_in,
                              void* d_out, int out_size, void* d_ws, size_t ws_size,
                              hipStream_t stream) {
  const float* x     = (const float*)d_in[0];   // [2,2048,2048] fp32
  const float* Wqkv  = (const float*)d_in[1];   // [6144,2048] fp32
  const float* Wproj = (const float*)d_in[2];   // [2048,2048] fp32
  float* out = (float*)d_out;                   // [2,2048,2048] fp32 = 32 MiB

  const int Bm = 4096, E = 2048;
  const size_t plane = 8388608;                 // 16 MiB as bf16

  bf16* qw  = (bf16*)d_ws;
  bf16* vtw = qw + plane;
  bf16* xb  = vtw + plane;       // later reused for Wproj bf16
  bf16* kw  = (bf16*)d_out;
  bf16* wqb = kw + plane;        // 2048 rows x 2048 = 8 MiB, fits d_out upper half

  // 1) x -> bf16
  conv_f32_bf16<<<8388608 / 2048, 256, 0, stream>>>(x, xb);
  // 2) QKV GEMM in 3 chunks of N=2048 (FROZEN 128x256 controls)
  for (int chunk = 0; chunk < 3; ++chunk) {
    conv_f32_bf16<<<4194304 / 2048, 256, 0, stream>>>(Wqkv + (size_t)chunk * 4194304, wqb);
    gemm_bt3<0, 1><<<dim3(2048 / 256, Bm / 128), 512, 0, stream>>>(
        xb, wqb, nullptr, qw, kw, vtw, Bm, 2048, E, chunk * 2048);
  }
  // 3) attention, two balanced dispatches (observability split)
  attn_kernel<<<dim3(8, 32), 256, 0, stream>>>(qw, kw, vtw, 2048, 0);
  attn_kernel<<<dim3(8, 32), 256, 0, stream>>>(qw, kw, vtw, 2048, 8);
  // 4) Wproj -> bf16 (xb region; xb dead)
  conv_f32_bf16<<<4194304 / 2048, 256, 0, stream>>>(Wproj, xb);
  // 5) proj GEMM: 256^2 4-deep rotating (A/B experiment), grid (8,16)=128 blocks
  gemm256r<2, 0><<<dim3(2048 / 256, Bm / 256), 512, 0, stream>>>(
      qw, xb, out, nullptr, nullptr, nullptr, Bm, 2048, E, 0);
}

// Round 8
// 412.560 us; speedup vs baseline: 1.1589x; 1.1589x over previous
//
#include <hip/hip_runtime.h>
#include <cstdint>
#include <cstddef>

typedef __bf16 bf16;
typedef __bf16 bf16x8 __attribute__((ext_vector_type(8)));
typedef float  f32x4  __attribute__((ext_vector_type(4)));

static_assert(sizeof(bf16x8) == 16, "bf16x8 must be 16B");

// async global->LDS, 16B per lane; lane i's data lands at ldsbase + i*16.
__device__ __forceinline__ void async_copy16(const bf16* g, bf16* l) {
  __builtin_amdgcn_global_load_lds(
      (__attribute__((address_space(1))) void*)(g),
      (__attribute__((address_space(3))) void*)(l),
      16, 0, 0);
}

// fp32 -> bf16 bulk convert, 8 elems/thread. n must be a multiple of 2048.
__global__ __launch_bounds__(256)
void conv_f32_bf16(const float* __restrict__ s, bf16* __restrict__ d) {
  const size_t i = ((size_t)blockIdx.x * 256 + threadIdx.x) * 8;
  const f32x4 a = *(const f32x4*)(s + i);
  const f32x4 b = *(const f32x4*)(s + i + 4);
  bf16x8 o;
#pragma unroll
  for (int e = 0; e < 4; ++e) { o[e] = (bf16)a[e]; o[4 + e] = (bf16)b[e]; }
  *(bf16x8*)(d + i) = o;
}

// ---------------------------------------------------------------------------
// C[m,n] = sum_k A[m,k] * W[n,k], all-bf16 m97-style: 128x128 tile, BK=64,
// async global->LDS both operands, XOR chunk swizzle (LDS[row][c]=G[row][c^(row&7)]).
// R8: __launch_bounds__(256,3) -> 3 blocks/CU (LDS 3x32KB=96KB, VGPR<=170).
// R2-R7 established per-block time ~= staged-bytes / per-CU staging rate, and
// the rate scales with INDEPENDENT blocks/CU (1->24, 2->28.6, 3->~50 GB/s,
// m97): intra-block barriers serialize stage/ds_read/MFMA; only co-resident
// blocks overlap them. Grids are sized for exactly 3/CU residency.
// AMODE 0: A row-major [M,K].  AMODE 2: A gathered from [B,H,S,D] plane.
// CMODE 0: C fp32 row-major -> Crow.
// CMODE 1: C scattered bf16; global col = nbase+n: <2048 -> Cq[b,h,s,d],
//          <4096 -> Ck[b,h,s,d], else -> Cvt TRANSPOSED [b,h,d,s].
// ---------------------------------------------------------------------------
template<int AMODE, int CMODE>
__global__ __launch_bounds__(256, 3)
void gemm_bt(const bf16* __restrict__ A, const bf16* __restrict__ W,
             float* __restrict__ Crow, bf16* __restrict__ Cq,
             bf16* __restrict__ Ck, bf16* __restrict__ Cvt,
             int M, int N, int K, int nbase) {
  __shared__ bf16 As[128 * 64];
  __shared__ bf16 Ws[128 * 64];

  const int tid  = threadIdx.x;
  const int wave = tid >> 6;
  const int lane = tid & 63;
  const int quad = lane >> 4;
  const int r    = lane & 15;

  // XCD-aware bijective swizzle (all launches have nwg % 8 == 0)
  const int gx  = gridDim.x;
  const int nwg = gx * gridDim.y;
  int wg = blockIdx.y * gx + blockIdx.x;
  wg = (wg & 7) * (nwg >> 3) + (wg >> 3);
  const int m0 = (wg / gx) * 128;
  const int n0 = (wg % gx) * 128;

  const int wm = (wave >> 1) * 64;
  const int wn = (wave & 1) * 64;

  const int lrow   = lane >> 3;      // 0..7
  const int gchunk = (lane & 7) ^ lrow;

  f32x4 acc[4][4] = {};

  for (int k0 = 0; k0 < K; k0 += 64) {
    __syncthreads();
    for (int j = 0; j < 4; ++j) {
      const int rbase = (wave * 4 + j) * 8;
      const int rowA  = m0 + rbase + lrow;
      const bf16* aSrc;
      if constexpr (AMODE == 2) {
        const int b = rowA >> 11, s = rowA & 2047;
        aSrc = A + ((size_t)(b * 16 + (k0 >> 7)) * 2048 + s) * 128
                 + (k0 & 127) + gchunk * 8;
      } else {
        aSrc = A + (size_t)rowA * K + k0 + gchunk * 8;
      }
      async_copy16(aSrc, As + rbase * 64);
      async_copy16(W + (size_t)(n0 + rbase + lrow) * K + k0 + gchunk * 8,
                   Ws + rbase * 64);
    }
    __syncthreads();
    for (int ks = 0; ks < 2; ++ks) {
      bf16x8 af[4], bfv[4];
      for (int i = 0; i < 4; ++i) {
        const int ar = wm + i * 16 + r;
        af[i]  = *(const bf16x8*)(As + ar * 64 + (((ks * 4 + quad) ^ (ar & 7)) * 8));
        const int br = wn + i * 16 + r;
        bfv[i] = *(const bf16x8*)(Ws + br * 64 + (((ks * 4 + quad) ^ (br & 7)) * 8));
      }
      for (int i = 0; i < 4; ++i)
        for (int j = 0; j < 4; ++j)
          acc[i][j] = __builtin_amdgcn_mfma_f32_16x16x32_bf16(af[i], bfv[j], acc[i][j], 0, 0, 0);
    }
  }

  // C-layout: row = quad*4+reg, col = lane&15 (m89-verified).
  for (int i = 0; i < 4; ++i) {
    const int growb = m0 + wm + i * 16 + quad * 4;
    for (int j = 0; j < 4; ++j) {
      const int gcol = n0 + wn + j * 16 + r;
      for (int rg = 0; rg < 4; ++rg) {
        const int grow = growb + rg;
        if constexpr (CMODE == 1) {
          const int gc = nbase + gcol;
          const int which = gc >> 11;
          const int h = (gc >> 7) & 15;
          const int d = gc & 127;
          const int b = grow >> 11;
          const int s = grow & 2047;
          const bf16 v = (bf16)acc[i][j][rg];
          if (which == 0)
            Cq[(((size_t)b * 16 + h) * 2048 + s) * 128 + d] = v;
          else if (which == 1)
            Ck[(((size_t)b * 16 + h) * 2048 + s) * 128 + d] = v;
          else
            Cvt[(((size_t)b * 16 + h) * 128 + d) * 2048 + s] = v;  // transposed
        } else {
          Crow[(size_t)grow * N + gcol] = acc[i][j][rg];
        }
      }
    }
  }
}

// Flash attention, causal (R5/R6 best: 107us). Q,K: [B*H, S, 128] bf16;
// Vt: [B*H, 128, S] bf16. O written IN-PLACE into the Q plane.
// QBLK=64, 4 waves, grid (16, B*H) = 512 blocks = 2 independent blocks/CU.
// Causal pairing: block i does 64-row q-tiles {31-i, i} -> uniform 33
// KV-tiles/block.
__global__ __launch_bounds__(256, 2)
void attn_kernel(bf16* __restrict__ Q, const bf16* __restrict__ K,
                 const bf16* __restrict__ Vt, int S) {
  __shared__ bf16 k_lds[2][64 * 128];   // [kv][d], swizzled   32 KB
  __shared__ bf16 v_lds[2][128 * 64];   // [d][kv], swizzled   32 KB
  __shared__ bf16 p_lds[4][16 * 64];    // per-wave P           8 KB

  const int tid = threadIdx.x, wave = tid >> 6, lane = tid & 63;
  const int quad = lane >> 4, r = lane & 15;
  const int bh = blockIdx.y;
  bf16* Qh = Q + (size_t)bh * S * 128;
  const bf16* Kh = K + (size_t)bh * S * 128;
  const bf16* Vth = Vt + (size_t)bh * 128 * S;

  const float sc = 0.0883883476483184f * 1.4426950408889634f; // 1/sqrt(128)*log2e

  auto issue_stage = [&](int kv0, int buf) {
#pragma unroll
    for (int j = 0; j < 4; ++j) {
      const int lin0 = j * 256 + wave * 64;       // wave-uniform
      const int lin = lin0 + lane;
      const int row = lin >> 4, ch = lin & 15;    // K: [64 kv][16 chunks]
      async_copy16(Kh + (size_t)(kv0 + row) * 128 + ((ch ^ (row & 7)) << 3),
                   &k_lds[buf][0] + lin0 * 8);
    }
#pragma unroll
    for (int j = 0; j < 4; ++j) {
      const int lin0 = j * 256 + wave * 64;
      const int lin = lin0 + lane;
      const int row = lin >> 3, c = lin & 7;      // V^T: [128 d][8 chunks]
      async_copy16(Vth + (size_t)row * S + kv0 + ((c ^ (row & 7)) << 3),
                   &v_lds[buf][0] + lin0 * 8);
    }
  };

  for (int pass = 0; pass < 2; ++pass) {
    const int qb = pass ? blockIdx.x : (31 - blockIdx.x);  // heavy tile first
    const int q0 = qb << 6;
    const int qrow0 = q0 + wave * 16;   // 16 q-rows per wave, 4 waves = 64
    const int nkv = qb + 1;

    bf16x8 qf[4];
    for (int ks = 0; ks < 4; ++ks)
      qf[ks] = *(const bf16x8*)(Qh + (size_t)(qrow0 + r) * 128 + ks * 32 + quad * 8);

    f32x4 o_acc[8] = {};
    f32x4 m_run, l_run;
    for (int t = 0; t < 4; ++t) { m_run[t] = -1e30f; l_run[t] = 0.f; }

    issue_stage(0, 0);  // prologue (prev pass fully drained by its tail)

    for (int kt = 0; kt < nkv; ++kt) {
      const int kv0 = kt << 6;
      const int cur = kt & 1;
      if (kt + 1 < nkv) {
        issue_stage((kt + 1) << 6, cur ^ 1);
        asm volatile("s_waitcnt vmcnt(8)" ::: "memory");  // cur tile resident
      } else {
        asm volatile("s_waitcnt vmcnt(0)" ::: "memory");
      }
      __builtin_amdgcn_sched_barrier(0);
      __syncthreads();

      {
        // S = Q K^T
        f32x4 sa[4] = {};
        __builtin_amdgcn_s_setprio(1);
        for (int ks = 0; ks < 4; ++ks) {
          bf16x8 kf[4];
          for (int nt = 0; nt < 4; ++nt) {
            const int kr = nt * 16 + r;
            kf[nt] = *(const bf16x8*)(&k_lds[cur][0] + kr * 128 + (((ks * 4 + quad) ^ (kr & 7)) << 3));
          }
          for (int nt = 0; nt < 4; ++nt)
            sa[nt] = __builtin_amdgcn_mfma_f32_16x16x32_bf16(qf[ks], kf[nt], sa[nt], 0, 0, 0);
        }
        __builtin_amdgcn_s_setprio(0);
        // causal mask on diagonal tiles
        if (kv0 + 63 > qrow0) {
          for (int nt = 0; nt < 4; ++nt) {
            const int col  = kv0 + nt * 16 + r;
            const int rowb = qrow0 + quad * 4;
            for (int rg = 0; rg < 4; ++rg)
              if (col > rowb + rg) sa[nt][rg] = -1e30f;
          }
        }
        // online softmax (each score row lives on the 16 lanes of one quad)
        f32x4 mx = sa[0];
        for (int nt = 1; nt < 4; ++nt)
          for (int rg = 0; rg < 4; ++rg) mx[rg] = fmaxf(mx[rg], sa[nt][rg]);
        for (int off = 1; off < 16; off <<= 1)
          for (int rg = 0; rg < 4; ++rg) mx[rg] = fmaxf(mx[rg], __shfl_xor(mx[rg], off, 64));
        // T13 defer-max: rescale only when growth is material (P <= 2^8).
        float need = mx[0] - m_run[0];
        for (int rg = 1; rg < 4; ++rg) need = fmaxf(need, mx[rg] - m_run[rg]);
        if (need * sc > 8.0f) {
          f32x4 alpha;
          for (int rg = 0; rg < 4; ++rg) {
            const float mnew = fmaxf(m_run[rg], mx[rg]);
            alpha[rg] = exp2f((m_run[rg] - mnew) * sc);
            m_run[rg] = mnew;
            l_run[rg] *= alpha[rg];
          }
          for (int nt2 = 0; nt2 < 8; ++nt2)
            for (int rg = 0; rg < 4; ++rg) o_acc[nt2][rg] *= alpha[rg];
        }
        f32x4 rsum = {0.f, 0.f, 0.f, 0.f};
        for (int nt = 0; nt < 4; ++nt)
          for (int rg = 0; rg < 4; ++rg) {
            const float p = exp2f((sa[nt][rg] - m_run[rg]) * sc);
            sa[nt][rg] = p;
            rsum[rg] += p;
          }
        for (int off = 1; off < 16; off <<= 1)
          for (int rg = 0; rg < 4; ++rg) rsum[rg] += __shfl_xor(rsum[rg], off, 64);
        for (int rg = 0; rg < 4; ++rg) l_run[rg] += rsum[rg];
        // P: C-layout -> A-layout via per-wave LDS round-trip, swizzled
        for (int nt = 0; nt < 4; ++nt)
          for (int rg = 0; rg < 4; ++rg) {
            const int prow = quad * 4 + rg;
            const int pcol = nt * 16 + r;
            p_lds[wave][prow * 64 + (((pcol >> 3) ^ (prow & 7)) * 8) + (pcol & 7)] =
                (bf16)sa[nt][rg];
          }
        // O += P V
        __builtin_amdgcn_s_setprio(1);
        for (int ks2 = 0; ks2 < 2; ++ks2) {
          const int prow = r;
          const bf16x8 pf = *(const bf16x8*)(p_lds[wave] + prow * 64 + (((ks2 * 4 + quad) ^ (prow & 7)) * 8));
          for (int nt2 = 0; nt2 < 8; ++nt2) {
            const int vrow = nt2 * 16 + r;
            const bf16x8 vf = *(const bf16x8*)(&v_lds[cur][0] + vrow * 64 + (((ks2 * 4 + quad) ^ (vrow & 7)) * 8));
            o_acc[nt2] = __builtin_amdgcn_mfma_f32_16x16x32_bf16(pf, vf, o_acc[nt2], 0, 0, 0);
          }
        }
        __builtin_amdgcn_s_setprio(0);
      }
      __syncthreads();
    }

    // epilogue: write O back into the Q plane, same [b,h,s,d] coords
    f32x4 inv;
    for (int rg = 0; rg < 4; ++rg) inv[rg] = 1.0f / l_run[rg];
    for (int nt2 = 0; nt2 < 8; ++nt2) {
      const int d = nt2 * 16 + r;
      for (int rg = 0; rg < 4; ++rg) {
        const int s = qrow0 + quad * 4 + rg;
        Qh[(size_t)s * 128 + d] = (bf16)(o_acc[nt2][rg] * inv[rg]);
      }
    }
  }
}

extern "C" void kernel_launch(void* const* d_in, const int* in_sizes, int n_in,
                              void* d_out, int out_size, void* d_ws, size_t ws_size,
                              hipStream_t stream) {
  const float* x     = (const float*)d_in[0];   // [2,2048,2048] fp32
  const float* Wqkv  = (const float*)d_in[1];   // [6144,2048] fp32
  const float* Wproj = (const float*)d_in[2];   // [2048,2048] fp32
  float* out = (float*)d_out;                   // [2,2048,2048] fp32 = 32 MiB

  const int Bm = 4096, E = 2048;
  const size_t plane = 8388608;                 // 16 MiB as bf16

  // ws (48 MiB): [0,plane) Q plane; [plane,2p) V^T plane; [2p,3p) xb then Wproj_bf16.
  // d_out (32 MiB): [0,plane) bf16 K plane; [plane,+6291456) bf16 Wqkv half
  //   (12 MiB); both dead before proj GEMM overwrites d_out with fp32 output.
  bf16* qw  = (bf16*)d_ws;
  bf16* vtw = qw + plane;
  bf16* xb  = vtw + plane;       // later reused for Wproj bf16
  bf16* kw  = (bf16*)d_out;
  bf16* wqb = kw + plane;        // 3072 rows x 2048 = 12 MiB, fits d_out upper half

  // 1) x -> bf16
  conv_f32_bf16<<<8388608 / 2048, 256, 0, stream>>>(x, xb);
  // 2) Wqkv rows [0,3072) -> bf16
  conv_f32_bf16<<<6291456 / 2048, 256, 0, stream>>>(Wqkv, wqb);
  // 3) QKV GEMM chunk A: n in [0,3072) -> all Q + K heads 0..7
  //    grid (24,32) = 768 blocks = exactly 3 blocks/CU, all resident
  gemm_bt<0, 1><<<dim3(3072 / 128, Bm / 128), 256, 0, stream>>>(
      xb, wqb, nullptr, qw, kw, vtw, Bm, 3072, E, 0);
  // 4) Wqkv rows [3072,6144) -> bf16 (overwrites wqb after chunk A)
  conv_f32_bf16<<<6291456 / 2048, 256, 0, stream>>>(Wqkv + 6291456, wqb);
  // 5) QKV GEMM chunk B: n in [3072,6144) -> K heads 8..15 + all V (transposed)
  gemm_bt<0, 1><<<dim3(3072 / 128, Bm / 128), 256, 0, stream>>>(
      xb, wqb, nullptr, qw, kw, vtw, Bm, 3072, E, 3072);
  // 6) attention (O overwrites Q plane); paired causal 64-row tiles,
  //    512 blocks = 2 independent blocks/CU
  attn_kernel<<<dim3(16, 32), 256, 0, stream>>>(qw, kw, vtw, 2048);
  // 7) Wproj -> bf16 (xb region; xb dead)
  conv_f32_bf16<<<4194304 / 2048, 256, 0, stream>>>(Wproj, xb);
  // 8) proj GEMM: A = O plane (gather), C = d_out fp32; grid (16,32)=512 blocks
  gemm_bt<2, 0><<<dim3(2048 / 128, Bm / 128), 256, 0, stream>>>(
      qw, xb, out, nullptr, nullptr, nullptr, Bm, 2048, E, 0);
}

// Round 9
// 406.864 us; speedup vs baseline: 1.1751x; 1.0140x over previous
//
#include <hip/hip_runtime.h>
#include <cstdint>
#include <cstddef>

typedef __bf16 bf16;
typedef __bf16 bf16x8 __attribute__((ext_vector_type(8)));
typedef float  f32x4  __attribute__((ext_vector_type(4)));

static_assert(sizeof(bf16x8) == 16, "bf16x8 must be 16B");

// async global->LDS, 16B per lane; lane i's data lands at ldsbase + i*16.
__device__ __forceinline__ void async_copy16(const bf16* g, bf16* l) {
  __builtin_amdgcn_global_load_lds(
      (__attribute__((address_space(1))) void*)(g),
      (__attribute__((address_space(3))) void*)(l),
      16, 0, 0);
}

__device__ __forceinline__ uint32_t lds_u32(const bf16* p) {
  return (uint32_t)(uintptr_t)((__attribute__((address_space(3))) const bf16*)p);
}

// fp32 -> bf16 bulk convert, 8 elems/thread. n must be a multiple of 2048.
__global__ __launch_bounds__(256)
void conv_f32_bf16(const float* __restrict__ s, bf16* __restrict__ d) {
  const size_t i = ((size_t)blockIdx.x * 256 + threadIdx.x) * 8;
  const f32x4 a = *(const f32x4*)(s + i);
  const f32x4 b = *(const f32x4*)(s + i + 4);
  bf16x8 o;
#pragma unroll
  for (int e = 0; e < 4; ++e) { o[e] = (bf16)a[e]; o[4 + e] = (bf16)b[e]; }
  *(bf16x8*)(d + i) = o;
}

// ---------------------------------------------------------------------------
// 256x256, BK=32, 4-deep rotating prefetch (R7-proven as proj; R9: now also
// QKV). Intensity = 256*256/(256+256) = 128 FLOP per staged byte — 2x the
// 128^2 tile. R7 measured ~805 TF per ACTIVE CU at this config; R9 exploits
// it with fuller grids (QKV chunks: 192 blocks = 75% fill).
// vmcnt ledger: 4 instrs/tile; phase t stages t+3 into buf (t+3)%4 (freed at
// end of phase t-1); vmcnt(8) allows tiles t+2,t+3 in flight, forces t+1
// (issued ~3 phases ago) landed. Tails 4 -> 0.
// ---------------------------------------------------------------------------
template<int AMODE>
__device__ __forceinline__ void stage256(const bf16* __restrict__ P, int K,
                                         int row0, int k0,
                                         bf16* lds, int wave, int lane) {
#pragma unroll
  for (int i = 0; i < 2; ++i) {
    const int lin0 = i * 512 + wave * 64;
    const int lin  = lin0 + lane;
    const int row  = lin >> 2;          // 0..255
    const int ch   = lin & 3;
    const int gch  = ch ^ ((row >> 1) & 3);
    const bf16* src;
    if constexpr (AMODE == 2) {
      const int rowA = row0 + row;
      const int b = rowA >> 11, s = rowA & 2047;
      src = P + ((size_t)(b * 16 + (k0 >> 7)) * 2048 + s) * 128 + (k0 & 127) + gch * 8;
    } else {
      src = P + (size_t)(row0 + row) * K + k0 + gch * 8;
    }
    async_copy16(src, lds + lin0 * 8);
  }
}

__device__ __forceinline__ void ld_frags84(uint32_t ab, uint32_t bb,
                                           bf16x8 (&a)[8], bf16x8 (&b)[4]) {
  asm volatile("ds_read_b128 %0, %1 offset:0"    : "=v"(a[0]) : "v"(ab));
  asm volatile("ds_read_b128 %0, %1 offset:1024" : "=v"(a[1]) : "v"(ab));
  asm volatile("ds_read_b128 %0, %1 offset:2048" : "=v"(a[2]) : "v"(ab));
  asm volatile("ds_read_b128 %0, %1 offset:3072" : "=v"(a[3]) : "v"(ab));
  asm volatile("ds_read_b128 %0, %1 offset:4096" : "=v"(a[4]) : "v"(ab));
  asm volatile("ds_read_b128 %0, %1 offset:5120" : "=v"(a[5]) : "v"(ab));
  asm volatile("ds_read_b128 %0, %1 offset:6144" : "=v"(a[6]) : "v"(ab));
  asm volatile("ds_read_b128 %0, %1 offset:7168" : "=v"(a[7]) : "v"(ab));
  asm volatile("ds_read_b128 %0, %1 offset:0"    : "=v"(b[0]) : "v"(bb));
  asm volatile("ds_read_b128 %0, %1 offset:1024" : "=v"(b[1]) : "v"(bb));
  asm volatile("ds_read_b128 %0, %1 offset:2048" : "=v"(b[2]) : "v"(bb));
  asm volatile("ds_read_b128 %0, %1 offset:3072" : "=v"(b[3]) : "v"(bb));
}

// AMODE 0: A row-major [M,K].  AMODE 2: A gathered from [B,H,S,D] plane.
// CMODE 0: C fp32 row-major -> Crow.
// CMODE 1: C scattered bf16; global col = nbase+n: <2048 -> Cq[b,h,s,d],
//          <4096 -> Ck[b,h,s,d], else -> Cvt TRANSPOSED [b,h,d,s].
template<int AMODE, int CMODE>
__global__ __launch_bounds__(512, 2)
void gemm256r(const bf16* __restrict__ A, const bf16* __restrict__ W,
              float* __restrict__ Crow, bf16* __restrict__ Cq,
              bf16* __restrict__ Ck, bf16* __restrict__ Cvt,
              int M, int N, int K, int nbase) {
  __shared__ bf16 As[4][256 * 32];
  __shared__ bf16 Ws[4][256 * 32];

  const int tid  = threadIdx.x;
  const int wave = tid >> 6, lane = tid & 63;
  const int quad = lane >> 4, r = lane & 15;
  const int wr = wave >> 2, wc = wave & 3;   // 2M x 4N, wave tile 128x64

  const int gx  = gridDim.x;
  const int nwg = gx * gridDim.y;
  int wg = blockIdx.y * gx + blockIdx.x;
  wg = (wg & 7) * (nwg >> 3) + (wg >> 3);    // bijective (nwg % 8 == 0)
  const int m0 = (wg / gx) * 256;
  const int n0 = (wg % gx) * 256;

  const int wm = wr * 128, wn = wc * 64;
  const int nT = K >> 5;
  const int cs = quad ^ ((r >> 1) & 3);

  f32x4 acc[8][4] = {};

  const uint32_t a_rd = lds_u32(&As[0][0]) + (((wm + r) * 32 + cs * 8) << 1);
  const uint32_t b_rd = lds_u32(&Ws[0][0]) + (((wn + r) * 32 + cs * 8) << 1);

  // prologue: stage tiles 0..2 (12 load-instrs)
#pragma unroll
  for (int i = 0; i < 3; ++i)
    if (i < nT) {
      stage256<AMODE>(A, K, m0, i << 5, &As[i][0], wave, lane);
      stage256<0>(W, K, n0, i << 5, &Ws[i][0], wave, lane);
    }
  if (nT > 2)       asm volatile("s_waitcnt vmcnt(8)" ::: "memory");
  else if (nT == 2) asm volatile("s_waitcnt vmcnt(4)" ::: "memory");
  else              asm volatile("s_waitcnt vmcnt(0)" ::: "memory");
  __builtin_amdgcn_sched_barrier(0);
  __builtin_amdgcn_s_barrier();

  int bc = 0;   // t % 4
  int bs = 3;   // (t+3) % 4
  for (int t = 0; t < nT; ++t) {
    bf16x8 af[8], bw[4];
    ld_frags84(a_rd + bc * 16384, b_rd + bc * 16384, af, bw);
    if (t + 3 < nT) {
      stage256<AMODE>(A, K, m0, (t + 3) << 5, &As[bs][0], wave, lane);
      stage256<0>(W, K, n0, (t + 3) << 5, &Ws[bs][0], wave, lane);
      asm volatile("s_waitcnt vmcnt(8)" ::: "memory");   // tile t+1 landed
    } else if (t + 3 == nT) {
      asm volatile("s_waitcnt vmcnt(4)" ::: "memory");
    } else {
      asm volatile("s_waitcnt vmcnt(0)" ::: "memory");
    }
    __builtin_amdgcn_sched_barrier(0);
    asm volatile("s_waitcnt lgkmcnt(0)" ::: "memory");
    __builtin_amdgcn_sched_barrier(0);
    __builtin_amdgcn_s_setprio(1);
#pragma unroll
    for (int m = 0; m < 8; ++m)
#pragma unroll
      for (int n = 0; n < 4; ++n)
        acc[m][n] = __builtin_amdgcn_mfma_f32_16x16x32_bf16(af[m], bw[n], acc[m][n], 0, 0, 0);
    __builtin_amdgcn_s_setprio(0);
    __builtin_amdgcn_s_barrier();
    bc = (bc + 1) & 3;
    bs = (bs + 1) & 3;
  }

#pragma unroll
  for (int i = 0; i < 8; ++i) {
    const int growb = m0 + wm + i * 16 + quad * 4;
#pragma unroll
    for (int j = 0; j < 4; ++j) {
      const int gcol = n0 + wn + j * 16 + r;
#pragma unroll
      for (int rg = 0; rg < 4; ++rg) {
        const int grow = growb + rg;
        if constexpr (CMODE == 1) {
          const int gc = nbase + gcol;
          const int which = gc >> 11;
          const int h = (gc >> 7) & 15;
          const int d = gc & 127;
          const int b = grow >> 11;
          const int s = grow & 2047;
          const bf16 v = (bf16)acc[i][j][rg];
          if (which == 0)
            Cq[(((size_t)b * 16 + h) * 2048 + s) * 128 + d] = v;
          else if (which == 1)
            Ck[(((size_t)b * 16 + h) * 2048 + s) * 128 + d] = v;
          else
            Cvt[(((size_t)b * 16 + h) * 128 + d) * 2048 + s] = v;
        } else {
          Crow[(size_t)grow * N + gcol] = acc[i][j][rg];
        }
      }
    }
  }
}

// ---------------------------------------------------------------------------
// 128(M) x 256(N), BK=32, 5-deep rotating (R6-proven: ~67us at full 256-block
// grid for the N=2048 shape). Used for proj (full grid (8,32)=256 blocks).
// ---------------------------------------------------------------------------
template<int AMODE>
__device__ __forceinline__ void stageA32(const bf16* __restrict__ P, int K,
                                         int row0, int k0,
                                         bf16* lds, int wave, int lane) {
  const int lin0 = wave * 64;           // wave-uniform
  const int lin  = lin0 + lane;
  const int row  = lin >> 2;            // 0..127
  const int ch   = lin & 3;
  const int gch  = ch ^ ((row >> 1) & 3);
  const bf16* src;
  if constexpr (AMODE == 2) {
    const int rowA = row0 + row;
    const int b = rowA >> 11, s = rowA & 2047;
    src = P + ((size_t)(b * 16 + (k0 >> 7)) * 2048 + s) * 128 + (k0 & 127) + gch * 8;
  } else {
    src = P + (size_t)(row0 + row) * K + k0 + gch * 8;
  }
  async_copy16(src, lds + lin0 * 8);
}

__device__ __forceinline__ void stageW32(const bf16* __restrict__ P, int K,
                                         int row0, int k0,
                                         bf16* lds, int wave, int lane) {
#pragma unroll
  for (int i = 0; i < 2; ++i) {
    const int lin0 = i * 512 + wave * 64;
    const int lin  = lin0 + lane;
    const int row  = lin >> 2;          // 0..255
    const int ch   = lin & 3;
    const int gch  = ch ^ ((row >> 1) & 3);
    async_copy16(P + (size_t)(row0 + row) * K + k0 + gch * 8,
                 lds + lin0 * 8);
  }
}

__device__ __forceinline__ void ld_frags(uint32_t ab, uint32_t bb,
                                         bf16x8 (&a)[4], bf16x8 (&b)[4]) {
  asm volatile("ds_read_b128 %0, %1 offset:0"    : "=v"(a[0]) : "v"(ab));
  asm volatile("ds_read_b128 %0, %1 offset:1024" : "=v"(a[1]) : "v"(ab));
  asm volatile("ds_read_b128 %0, %1 offset:2048" : "=v"(a[2]) : "v"(ab));
  asm volatile("ds_read_b128 %0, %1 offset:3072" : "=v"(a[3]) : "v"(ab));
  asm volatile("ds_read_b128 %0, %1 offset:0"    : "=v"(b[0]) : "v"(bb));
  asm volatile("ds_read_b128 %0, %1 offset:1024" : "=v"(b[1]) : "v"(bb));
  asm volatile("ds_read_b128 %0, %1 offset:2048" : "=v"(b[2]) : "v"(bb));
  asm volatile("ds_read_b128 %0, %1 offset:3072" : "=v"(b[3]) : "v"(bb));
}

template<int AMODE, int CMODE>
__global__ __launch_bounds__(512, 2)
void gemm_bt3(const bf16* __restrict__ A, const bf16* __restrict__ W,
              float* __restrict__ Crow, bf16* __restrict__ Cq,
              bf16* __restrict__ Ck, bf16* __restrict__ Cvt,
              int M, int N, int K, int nbase) {
  __shared__ bf16 As[5][128 * 32];
  __shared__ bf16 Ws[5][256 * 32];

  const int tid  = threadIdx.x;
  const int wave = tid >> 6, lane = tid & 63;
  const int quad = lane >> 4, r = lane & 15;
  const int wr = wave >> 2, wc = wave & 3;   // 2M x 4N wave grid

  const int gx  = gridDim.x;
  const int nwg = gx * gridDim.y;
  int wg = blockIdx.y * gx + blockIdx.x;
  wg = (wg & 7) * (nwg >> 3) + (wg >> 3);
  const int m0 = (wg / gx) * 128;
  const int n0 = (wg % gx) * 256;

  const int wm = wr * 64, wn = wc * 64;
  const int nT = K >> 5;
  const int cs = quad ^ ((r >> 1) & 3);      // read chunk (A and W)

  f32x4 acc[4][4] = {};

  const uint32_t a_rd = lds_u32(&As[0][0]) + (((wm + r) * 32 + cs * 8) << 1);
  const uint32_t b_rd = lds_u32(&Ws[0][0]) + (((wn + r) * 32 + cs * 8) << 1);

  // prologue: stage tiles 0..3 (12 load-instrs)
#pragma unroll
  for (int i = 0; i < 4; ++i)
    if (i < nT) {
      stageA32<AMODE>(A, K, m0, i << 5, &As[i][0], wave, lane);
      stageW32(W, K, n0, i << 5, &Ws[i][0], wave, lane);
    }
  if (nT > 3)       asm volatile("s_waitcnt vmcnt(9)" ::: "memory");
  else if (nT == 3) asm volatile("s_waitcnt vmcnt(6)" ::: "memory");
  else if (nT == 2) asm volatile("s_waitcnt vmcnt(3)" ::: "memory");
  else              asm volatile("s_waitcnt vmcnt(0)" ::: "memory");
  __builtin_amdgcn_sched_barrier(0);
  __builtin_amdgcn_s_barrier();

  int bc = 0;   // t % 5 (read buf)
  int bs = 4;   // (t+4) % 5 (stage buf)
  for (int t = 0; t < nT; ++t) {
    bf16x8 af[4], bw[4];
    ld_frags(a_rd + bc * 8192, b_rd + bc * 16384, af, bw);
    if (t + 4 < nT) {
      stageA32<AMODE>(A, K, m0, (t + 4) << 5, &As[bs][0], wave, lane);
      stageW32(W, K, n0, (t + 4) << 5, &Ws[bs][0], wave, lane);
      asm volatile("s_waitcnt vmcnt(9)" ::: "memory");   // tile t+1 landed
    } else if (t + 4 == nT) {
      asm volatile("s_waitcnt vmcnt(6)" ::: "memory");
    } else if (t + 3 == nT) {
      asm volatile("s_waitcnt vmcnt(3)" ::: "memory");
    } else {
      asm volatile("s_waitcnt vmcnt(0)" ::: "memory");
    }
    __builtin_amdgcn_sched_barrier(0);
    asm volatile("s_waitcnt lgkmcnt(0)" ::: "memory");
    __builtin_amdgcn_sched_barrier(0);
    __builtin_amdgcn_s_setprio(1);
#pragma unroll
    for (int m = 0; m < 4; ++m)
#pragma unroll
      for (int n = 0; n < 4; ++n)
        acc[m][n] = __builtin_amdgcn_mfma_f32_16x16x32_bf16(af[m], bw[n], acc[m][n], 0, 0, 0);
    __builtin_amdgcn_s_setprio(0);
    __builtin_amdgcn_s_barrier();
    bc = (bc + 1 == 5) ? 0 : bc + 1;
    bs = (bs + 1 == 5) ? 0 : bs + 1;
  }

#pragma unroll
  for (int i = 0; i < 4; ++i) {
    const int growb = m0 + wm + i * 16 + quad * 4;
#pragma unroll
    for (int j = 0; j < 4; ++j) {
      const int gcol = n0 + wn + j * 16 + r;
#pragma unroll
      for (int rg = 0; rg < 4; ++rg) {
        const int grow = growb + rg;
        if constexpr (CMODE == 1) {
          const int gc = nbase + gcol;
          const int which = gc >> 11;
          const int h = (gc >> 7) & 15;
          const int d = gc & 127;
          const int b = grow >> 11;
          const int s = grow & 2047;
          const bf16 v = (bf16)acc[i][j][rg];
          if (which == 0)
            Cq[(((size_t)b * 16 + h) * 2048 + s) * 128 + d] = v;
          else if (which == 1)
            Ck[(((size_t)b * 16 + h) * 2048 + s) * 128 + d] = v;
          else
            Cvt[(((size_t)b * 16 + h) * 128 + d) * 2048 + s] = v;
        } else {
          Crow[(size_t)grow * N + gcol] = acc[i][j][rg];
        }
      }
    }
  }
}

// Flash attention, causal (R5-proven: 107us). Q,K: [B*H, S, 128] bf16;
// Vt: [B*H, 128, S] bf16. O written IN-PLACE into the Q plane.
// QBLK=64, 4 waves, grid (16, B*H) = 512 blocks = 2 independent blocks/CU.
__global__ __launch_bounds__(256, 2)
void attn_kernel(bf16* __restrict__ Q, const bf16* __restrict__ K,
                 const bf16* __restrict__ Vt, int S) {
  __shared__ bf16 k_lds[2][64 * 128];   // [kv][d], swizzled   32 KB
  __shared__ bf16 v_lds[2][128 * 64];   // [d][kv], swizzled   32 KB
  __shared__ bf16 p_lds[4][16 * 64];    // per-wave P           8 KB

  const int tid = threadIdx.x, wave = tid >> 6, lane = tid & 63;
  const int quad = lane >> 4, r = lane & 15;
  const int bh = blockIdx.y;
  bf16* Qh = Q + (size_t)bh * S * 128;
  const bf16* Kh = K + (size_t)bh * S * 128;
  const bf16* Vth = Vt + (size_t)bh * 128 * S;

  const float sc = 0.0883883476483184f * 1.4426950408889634f; // 1/sqrt(128)*log2e

  auto issue_stage = [&](int kv0, int buf) {
#pragma unroll
    for (int j = 0; j < 4; ++j) {
      const int lin0 = j * 256 + wave * 64;       // wave-uniform
      const int lin = lin0 + lane;
      const int row = lin >> 4, ch = lin & 15;    // K: [64 kv][16 chunks]
      async_copy16(Kh + (size_t)(kv0 + row) * 128 + ((ch ^ (row & 7)) << 3),
                   &k_lds[buf][0] + lin0 * 8);
    }
#pragma unroll
    for (int j = 0; j < 4; ++j) {
      const int lin0 = j * 256 + wave * 64;
      const int lin = lin0 + lane;
      const int row = lin >> 3, c = lin & 7;      // V^T: [128 d][8 chunks]
      async_copy16(Vth + (size_t)row * S + kv0 + ((c ^ (row & 7)) << 3),
                   &v_lds[buf][0] + lin0 * 8);
    }
  };

  for (int pass = 0; pass < 2; ++pass) {
    const int qb = pass ? blockIdx.x : (31 - blockIdx.x);  // heavy tile first
    const int q0 = qb << 6;
    const int qrow0 = q0 + wave * 16;   // 16 q-rows per wave, 4 waves = 64
    const int nkv = qb + 1;

    bf16x8 qf[4];
    for (int ks = 0; ks < 4; ++ks)
      qf[ks] = *(const bf16x8*)(Qh + (size_t)(qrow0 + r) * 128 + ks * 32 + quad * 8);

    f32x4 o_acc[8] = {};
    f32x4 m_run, l_run;
    for (int t = 0; t < 4; ++t) { m_run[t] = -1e30f; l_run[t] = 0.f; }

    issue_stage(0, 0);  // prologue (prev pass fully drained by its tail)

    for (int kt = 0; kt < nkv; ++kt) {
      const int kv0 = kt << 6;
      const int cur = kt & 1;
      if (kt + 1 < nkv) {
        issue_stage((kt + 1) << 6, cur ^ 1);
        asm volatile("s_waitcnt vmcnt(8)" ::: "memory");  // cur tile resident
      } else {
        asm volatile("s_waitcnt vmcnt(0)" ::: "memory");
      }
      __builtin_amdgcn_sched_barrier(0);
      __syncthreads();

      {
        // S = Q K^T
        f32x4 sa[4] = {};
        __builtin_amdgcn_s_setprio(1);
        for (int ks = 0; ks < 4; ++ks) {
          bf16x8 kf[4];
          for (int nt = 0; nt < 4; ++nt) {
            const int kr = nt * 16 + r;
            kf[nt] = *(const bf16x8*)(&k_lds[cur][0] + kr * 128 + (((ks * 4 + quad) ^ (kr & 7)) << 3));
          }
          for (int nt = 0; nt < 4; ++nt)
            sa[nt] = __builtin_amdgcn_mfma_f32_16x16x32_bf16(qf[ks], kf[nt], sa[nt], 0, 0, 0);
        }
        __builtin_amdgcn_s_setprio(0);
        // causal mask on diagonal tiles
        if (kv0 + 63 > qrow0) {
          for (int nt = 0; nt < 4; ++nt) {
            const int col  = kv0 + nt * 16 + r;
            const int rowb = qrow0 + quad * 4;
            for (int rg = 0; rg < 4; ++rg)
              if (col > rowb + rg) sa[nt][rg] = -1e30f;
          }
        }
        // online softmax (each score row lives on the 16 lanes of one quad)
        f32x4 mx = sa[0];
        for (int nt = 1; nt < 4; ++nt)
          for (int rg = 0; rg < 4; ++rg) mx[rg] = fmaxf(mx[rg], sa[nt][rg]);
        for (int off = 1; off < 16; off <<= 1)
          for (int rg = 0; rg < 4; ++rg) mx[rg] = fmaxf(mx[rg], __shfl_xor(mx[rg], off, 64));
        // T13 defer-max: rescale only when growth is material (P <= 2^8).
        float need = mx[0] - m_run[0];
        for (int rg = 1; rg < 4; ++rg) need = fmaxf(need, mx[rg] - m_run[rg]);
        if (need * sc > 8.0f) {
          f32x4 alpha;
          for (int rg = 0; rg < 4; ++rg) {
            const float mnew = fmaxf(m_run[rg], mx[rg]);
            alpha[rg] = exp2f((m_run[rg] - mnew) * sc);
            m_run[rg] = mnew;
            l_run[rg] *= alpha[rg];
          }
          for (int nt2 = 0; nt2 < 8; ++nt2)
            for (int rg = 0; rg < 4; ++rg) o_acc[nt2][rg] *= alpha[rg];
        }
        f32x4 rsum = {0.f, 0.f, 0.f, 0.f};
        for (int nt = 0; nt < 4; ++nt)
          for (int rg = 0; rg < 4; ++rg) {
            const float p = exp2f((sa[nt][rg] - m_run[rg]) * sc);
            sa[nt][rg] = p;
            rsum[rg] += p;
          }
        for (int off = 1; off < 16; off <<= 1)
          for (int rg = 0; rg < 4; ++rg) rsum[rg] += __shfl_xor(rsum[rg], off, 64);
        for (int rg = 0; rg < 4; ++rg) l_run[rg] += rsum[rg];
        // P: C-layout -> A-layout via per-wave LDS round-trip, swizzled
        for (int nt = 0; nt < 4; ++nt)
          for (int rg = 0; rg < 4; ++rg) {
            const int prow = quad * 4 + rg;
            const int pcol = nt * 16 + r;
            p_lds[wave][prow * 64 + (((pcol >> 3) ^ (prow & 7)) * 8) + (pcol & 7)] =
                (bf16)sa[nt][rg];
          }
        // O += P V
        __builtin_amdgcn_s_setprio(1);
        for (int ks2 = 0; ks2 < 2; ++ks2) {
          const int prow = r;
          const bf16x8 pf = *(const bf16x8*)(p_lds[wave] + prow * 64 + (((ks2 * 4 + quad) ^ (prow & 7)) * 8));
          for (int nt2 = 0; nt2 < 8; ++nt2) {
            const int vrow = nt2 * 16 + r;
            const bf16x8 vf = *(const bf16x8*)(&v_lds[cur][0] + vrow * 64 + (((ks2 * 4 + quad) ^ (vrow & 7)) * 8));
            o_acc[nt2] = __builtin_amdgcn_mfma_f32_16x16x32_bf16(pf, vf, o_acc[nt2], 0, 0, 0);
          }
        }
        __builtin_amdgcn_s_setprio(0);
      }
      __syncthreads();
    }

    // epilogue: write O back into the Q plane, same [b,h,s,d] coords
    f32x4 inv;
    for (int rg = 0; rg < 4; ++rg) inv[rg] = 1.0f / l_run[rg];
    for (int nt2 = 0; nt2 < 8; ++nt2) {
      const int d = nt2 * 16 + r;
      for (int rg = 0; rg < 4; ++rg) {
        const int s = qrow0 + quad * 4 + rg;
        Qh[(size_t)s * 128 + d] = (bf16)(o_acc[nt2][rg] * inv[rg]);
      }
    }
  }
}

extern "C" void kernel_launch(void* const* d_in, const int* in_sizes, int n_in,
                              void* d_out, int out_size, void* d_ws, size_t ws_size,
                              hipStream_t stream) {
  const float* x     = (const float*)d_in[0];   // [2,2048,2048] fp32
  const float* Wqkv  = (const float*)d_in[1];   // [6144,2048] fp32
  const float* Wproj = (const float*)d_in[2];   // [2048,2048] fp32
  float* out = (float*)d_out;                   // [2,2048,2048] fp32 = 32 MiB

  const int Bm = 4096, E = 2048;
  const size_t plane = 8388608;                 // 16 MiB as bf16

  // ws (48 MiB): [0,plane) Q plane; [plane,2p) V^T plane; [2p,3p) xb then Wproj_bf16.
  // d_out (32 MiB): [0,plane) bf16 K plane; [plane,+6291456) bf16 Wqkv half
  //   (12 MiB); both dead before proj GEMM overwrites d_out with fp32 output.
  bf16* qw  = (bf16*)d_ws;
  bf16* vtw = qw + plane;
  bf16* xb  = vtw + plane;       // later reused for Wproj bf16
  bf16* kw  = (bf16*)d_out;
  bf16* wqb = kw + plane;        // 3072 rows x 2048 = 12 MiB, fits d_out upper half

  // 1) x -> bf16
  conv_f32_bf16<<<8388608 / 2048, 256, 0, stream>>>(x, xb);
  // 2) Wqkv rows [0,3072) -> bf16
  conv_f32_bf16<<<6291456 / 2048, 256, 0, stream>>>(Wqkv, wqb);
  // 3) QKV GEMM chunk A (256^2 tiles, intensity 128 FLOP/B): grid (12,16)=192
  gemm256r<0, 1><<<dim3(3072 / 256, Bm / 256), 512, 0, stream>>>(
      xb, wqb, nullptr, qw, kw, vtw, Bm, 3072, E, 0);
  // 4) Wqkv rows [3072,6144) -> bf16 (overwrites wqb after chunk A)
  conv_f32_bf16<<<6291456 / 2048, 256, 0, stream>>>(Wqkv + 6291456, wqb);
  // 5) QKV GEMM chunk B: n in [3072,6144) -> K heads 8..15 + all V (transposed)
  gemm256r<0, 1><<<dim3(3072 / 256, Bm / 256), 512, 0, stream>>>(
      xb, wqb, nullptr, qw, kw, vtw, Bm, 3072, E, 3072);
  // 6) attention (O overwrites Q plane); paired causal 64-row tiles,
  //    512 blocks = 2 independent blocks/CU
  attn_kernel<<<dim3(16, 32), 256, 0, stream>>>(qw, kw, vtw, 2048);
  // 7) Wproj -> bf16 (xb region; xb dead)
  conv_f32_bf16<<<4194304 / 2048, 256, 0, stream>>>(Wproj, xb);
  // 8) proj GEMM: 128x256 tiles at FULL grid (8,32)=256 blocks (R6-proven 67us)
  gemm_bt3<2, 0><<<dim3(2048 / 256, Bm / 128), 512, 0, stream>>>(
      qw, xb, out, nullptr, nullptr, nullptr, Bm, 2048, E, 0);
}